// Round 2
// baseline (91079.462 us; speedup 1.0000x reference)
//
#include <hip/hip_runtime.h>
#include <hip/hip_bf16.h>

typedef unsigned int u32;
typedef unsigned short u16;
using half2_t = __attribute__((ext_vector_type(2))) _Float16;
using half8   = __attribute__((ext_vector_type(8))) _Float16;
using f32x4   = __attribute__((ext_vector_type(4))) float;

// Problem dims
#define TT 16384
#define HDIM 2048
#define N3H 6144
#define ODIM 1000

// Workspace layout (bytes). Total = 318,785,536 (~304 MB)
#define WS_WPACK 0ull                 // 25,165,824  : W_hh packed f16 pairs
#define WS_XH    25165824ull          // 67,108,864  : x as f16
#define WS_WIHH  92274688ull          // 25,165,824  : W_ih as f16
#define WS_IG    117440512ull         // 201,326,592 : igates f16 [T][6144]
#define WS_PAIR  318767104ull         // 16,384      : h publish {tag16|f16} [2][2048] u32
#define WS_NEED  318785536ull

#if __has_builtin(__builtin_amdgcn_fdot2)
__device__ __forceinline__ float fdot2u(u32 a, u32 b, float c) {
  return __builtin_amdgcn_fdot2(__builtin_bit_cast(half2_t, a),
                                __builtin_bit_cast(half2_t, b), c, false);
}
#else
__device__ __forceinline__ float fdot2u(u32 a, u32 b, float c) {
  half2_t x = __builtin_bit_cast(half2_t, a), y = __builtin_bit_cast(half2_t, b);
  return c + (float)x[0] * (float)y[0] + (float)x[1] * (float)y[1];
}
#endif

// ---------------- zero the publish buffers (every launch: clears stale tags) -
__global__ void k_zero(u32* p) {
  p[blockIdx.x * 256 + threadIdx.x] = 0u;  // 4096 dwords
}

// ---------------- fp32 -> f16 convert, 4 elems/thread ------------------------
__global__ __launch_bounds__(256) void k_conv_f16(const float* __restrict__ in,
                                                  _Float16* __restrict__ out,
                                                  int n4) {
  int i = blockIdx.x * 256 + threadIdx.x;
  if (i >= n4) return;
  float4 v = ((const float4*)in)[i];
  u32 lo = (u32)__builtin_bit_cast(u16, (_Float16)v.x) |
           ((u32)__builtin_bit_cast(u16, (_Float16)v.y) << 16);
  u32 hi = (u32)__builtin_bit_cast(u16, (_Float16)v.z) |
           ((u32)__builtin_bit_cast(u16, (_Float16)v.w) << 16);
  ((uint2*)out)[i] = make_uint2(lo, hi);
}

// ---------------- pack W_hh into per-(hrow,wave,lane) f16-pair layout --------
__global__ __launch_bounds__(256) void k_pack(const float* __restrict__ whh,
                                              u32* __restrict__ outp) {
  u32 idx = blockIdx.x * 256 + threadIdx.x;  // < 6,291,456
  u32 hrow = idx / 3072;
  u32 rem = idx - hrow * 3072;
  u32 c = rem >> 8;
  u32 lane = (rem >> 2) & 63;
  u32 q = rem & 3;
  u32 dl = c * 4 + q;
  u32 g = dl >> 4;
  u32 m = dl & 15;
  u32 kp = lane * 16 + m;
  const float* src = whh + (size_t)(g * 2048 + hrow) * 2048 + 2 * kp;
  half2_t p;
  p[0] = (_Float16)src[0];
  p[1] = (_Float16)src[1];
  outp[idx] = __builtin_bit_cast(u32, p);
}

// ---------------- igates GEMM: C[m][n] = sum_k x[m][k]*Wih[n][k] + bias[n] ----
__global__ __launch_bounds__(256) void k_gemm(const _Float16* __restrict__ A,
                                              const _Float16* __restrict__ B,
                                              const float* __restrict__ bias,
                                              _Float16* __restrict__ Cout) {
  __shared__ __align__(16) _Float16 As[128 * 32];
  __shared__ __align__(16) _Float16 Bs[128 * 32];
  const int tid = threadIdx.x;
  const int l = tid & 63, w = tid >> 6;
  const int wr = w >> 1, wc = w & 1;
  const int m0 = blockIdx.x * 128, n0 = blockIdx.y * 128;
  const int srow = tid >> 2;
  const int scol = (tid & 3) << 3;
  f32x4 acc[4][4] = {};

  for (int k0 = 0; k0 < HDIM; k0 += 32) {
    __syncthreads();
    uint4 a0 = *(const uint4*)(A + (size_t)(m0 + srow) * HDIM + k0 + scol);
    uint4 a1 = *(const uint4*)(A + (size_t)(m0 + 64 + srow) * HDIM + k0 + scol);
    uint4 b0 = *(const uint4*)(B + (size_t)(n0 + srow) * HDIM + k0 + scol);
    uint4 b1 = *(const uint4*)(B + (size_t)(n0 + 64 + srow) * HDIM + k0 + scol);
    *(uint4*)(As + srow * 32 + scol) = a0;
    *(uint4*)(As + (64 + srow) * 32 + scol) = a1;
    *(uint4*)(Bs + srow * 32 + scol) = b0;
    *(uint4*)(Bs + (64 + srow) * 32 + scol) = b1;
    __syncthreads();
    half8 av[4], bv[4];
#pragma unroll
    for (int mi = 0; mi < 4; ++mi)
      av[mi] = *(const half8*)(As + (wr * 64 + mi * 16 + (l & 15)) * 32 + (l >> 4) * 8);
#pragma unroll
    for (int ni = 0; ni < 4; ++ni)
      bv[ni] = *(const half8*)(Bs + (wc * 64 + ni * 16 + (l & 15)) * 32 + (l >> 4) * 8);
#pragma unroll
    for (int mi = 0; mi < 4; ++mi)
#pragma unroll
      for (int ni = 0; ni < 4; ++ni)
        acc[mi][ni] = __builtin_amdgcn_mfma_f32_16x16x32_f16(av[mi], bv[ni], acc[mi][ni], 0, 0, 0);
  }
#pragma unroll
  for (int ni = 0; ni < 4; ++ni) {
    int col = n0 + wc * 64 + ni * 16 + (l & 15);
    float bb = bias[col];
#pragma unroll
    for (int mi = 0; mi < 4; ++mi) {
      int rbase = m0 + wr * 64 + mi * 16 + (l >> 4) * 4;
#pragma unroll
      for (int r = 0; r < 4; ++r)
        Cout[(size_t)(rbase + r) * N3H + col] = (_Float16)(acc[mi][ni][r] + bb);
    }
  }
}

// ---------------- persistent GRU scan: 256 WGs x 512 thr, coop launch --------
// Wave w of WG wg owns h-row hrow = wg*8+w. W_hh slice in registers.
// Sync: h published as one atomic dword {tag:u16 = t+1 | value:f16}.
// Consumers poll tag match directly -> value present. No counters, no fences.
__global__ __launch_bounds__(512) void k_scan(const uint4* __restrict__ wpack,
                                              const _Float16* __restrict__ ig,
                                              const float* __restrict__ bias_n,
                                              u32* pair) {
  __shared__ __align__(16) u32 lds_h[1280];  // 1024 f16-pair dwords + pad 4/16
  const int tid = threadIdx.x;
  const int l = tid & 63, w = tid >> 6;
  const int wg = blockIdx.x;
  const int hrow = wg * 8 + w;

  u32 wdw[48];
  {
    const uint4* wp = wpack + (size_t)hrow * 12 * 64 + l;
#pragma unroll
    for (int c = 0; c < 12; ++c) {
      uint4 v = wp[(size_t)c * 64];
      wdw[c * 4] = v.x; wdw[c * 4 + 1] = v.y; wdw[c * 4 + 2] = v.z; wdw[c * 4 + 3] = v.w;
    }
  }
  const float bn = bias_n[hrow];
  float hm = 0.f;  // fp32 master state (valid in lane 0)
  u32 hreg[16];
#pragma unroll
  for (int m = 0; m < 16; ++m) hreg[m] = 0;  // h(0) = 0

  float ig0 = (float)ig[hrow], ig1 = (float)ig[2048 + hrow], ig2 = (float)ig[4096 + hrow];

  for (int t = 0; t < TT; ++t) {
    float igr = ig0, igz = ig1, ign = ig2;
    float a0 = 0.f, a1 = 0.f, a2 = 0.f, b0 = 0.f, b1 = 0.f, b2 = 0.f;
#pragma unroll
    for (int m = 0; m < 16; m += 2) {
      a0 = fdot2u(wdw[m],          hreg[m],     a0);
      b0 = fdot2u(wdw[m + 1],      hreg[m + 1], b0);
      a1 = fdot2u(wdw[16 + m],     hreg[m],     a1);
      b1 = fdot2u(wdw[16 + m + 1], hreg[m + 1], b1);
      a2 = fdot2u(wdw[32 + m],     hreg[m],     a2);
      b2 = fdot2u(wdw[32 + m + 1], hreg[m + 1], b2);
    }
    float s0 = a0 + b0, s1 = a1 + b1, s2 = a2 + b2;
#pragma unroll
    for (int off = 1; off < 64; off <<= 1) {
      s0 += __shfl_xor(s0, off, 64);
      s1 += __shfl_xor(s1, off, 64);
      s2 += __shfl_xor(s2, off, 64);
    }
    u32* pdst = pair + (((t + 1) & 1) << 11);
    if (l == 0) {
      float r = 1.f / (1.f + __expf(-(igr + s0)));
      float z = 1.f / (1.f + __expf(-(igz + s1)));
      float nx = ign + r * (s2 + bn);
      float e = __expf(-2.f * nx);
      float n = (1.f - e) / (1.f + e);
      hm = n + z * (hm - n);
      u32 pk = ((u32)(t + 1) << 16) | (u32)__builtin_bit_cast(u16, (_Float16)hm);
      __hip_atomic_store(pdst + hrow, pk, __ATOMIC_RELAXED, __HIP_MEMORY_SCOPE_AGENT);
    }
    if (t == TT - 1) break;
    {  // prefetch next igates row (normal cached loads, latency hidden by poll)
      const _Float16* igp = ig + (size_t)(t + 1) * N3H;
      ig0 = (float)igp[hrow]; ig1 = (float)igp[2048 + hrow]; ig2 = (float)igp[4096 + hrow];
    }
    // poll own 4 rows until all tags == t+1 (value rides in the same dword)
    const u32 tgt = (u32)(t + 1) << 16;
    const u32* pp = pdst + 4 * tid;
    u32 d0, d1, d2, d3;
    for (;;) {
      d0 = __hip_atomic_load(pp + 0, __ATOMIC_RELAXED, __HIP_MEMORY_SCOPE_AGENT);
      d1 = __hip_atomic_load(pp + 1, __ATOMIC_RELAXED, __HIP_MEMORY_SCOPE_AGENT);
      d2 = __hip_atomic_load(pp + 2, __ATOMIC_RELAXED, __HIP_MEMORY_SCOPE_AGENT);
      d3 = __hip_atomic_load(pp + 3, __ATOMIC_RELAXED, __HIP_MEMORY_SCOPE_AGENT);
      u32 bad = ((d0 ^ tgt) | (d1 ^ tgt) | (d2 ^ tgt) | (d3 ^ tgt)) & 0xFFFF0000u;
      if (!bad) break;
    }
    __syncthreads();  // all local waves done reading lds_h of prev step
    u32 p0 = (d0 & 0xFFFFu) | (d1 << 16);
    u32 p1 = (d2 & 0xFFFFu) | (d3 << 16);
    u32* dst = lds_h + 2 * tid + ((tid >> 3) << 2);  // pad 4 dwords per 16
    dst[0] = p0;
    dst[1] = p1;
    __syncthreads();
#pragma unroll
    for (int i = 0; i < 4; ++i) {
      uint4 v = *(const uint4*)(lds_h + l * 20 + i * 4);
      hreg[i * 4] = v.x; hreg[i * 4 + 1] = v.y; hreg[i * 4 + 2] = v.z; hreg[i * 4 + 3] = v.w;
    }
  }
}

// ---------------- final projection: out = w_out @ h_final + b_out + b_extra --
// h_final is in pair buffer 0 (TT even), f16 in low 16 bits of each dword.
__global__ __launch_bounds__(256) void k_out(const float* __restrict__ wout,
                                             const float* __restrict__ bout,
                                             const float* __restrict__ bextra,
                                             const u32* __restrict__ hp,
                                             float* __restrict__ out) {
  const int l = threadIdx.x & 63;
  const int o = blockIdx.x * 4 + (threadIdx.x >> 6);
  if (o >= ODIM) return;
  const float* wr = wout + (size_t)o * HDIM;
  float acc = 0.f;
#pragma unroll
  for (int i = 0; i < 8; ++i) {
    int k4 = i * 256 + l * 4;
    uint4 hd = *(const uint4*)(hp + k4);
    float4 wv = *(const float4*)(wr + k4);
    acc += wv.x * (float)__builtin_bit_cast(_Float16, (u16)(hd.x & 0xFFFFu));
    acc += wv.y * (float)__builtin_bit_cast(_Float16, (u16)(hd.y & 0xFFFFu));
    acc += wv.z * (float)__builtin_bit_cast(_Float16, (u16)(hd.z & 0xFFFFu));
    acc += wv.w * (float)__builtin_bit_cast(_Float16, (u16)(hd.w & 0xFFFFu));
  }
#pragma unroll
  for (int off = 1; off < 64; off <<= 1) acc += __shfl_xor(acc, off, 64);
  if (l == 0) out[o] = acc + bout[o] + bextra[o];
}

// sentinel if workspace too small: absmax ~= 1e6 + ws_size_in_MB (debug channel)
__global__ void k_dbg(float* out, float v) {
  int i = blockIdx.x * 256 + threadIdx.x;
  if (i < ODIM) out[i] = v;
}

extern "C" void kernel_launch(void* const* d_in, const int* in_sizes, int n_in,
                              void* d_out, int out_size, void* d_ws, size_t ws_size,
                              hipStream_t stream) {
  const float* x      = (const float*)d_in[0];
  const float* wih    = (const float*)d_in[1];
  const float* whh    = (const float*)d_in[2];
  const float* bias   = (const float*)d_in[3];
  const float* bias_n = (const float*)d_in[4];
  const float* wout   = (const float*)d_in[5];
  const float* bout   = (const float*)d_in[6];
  const float* bextra = (const float*)d_in[7];
  float* out = (float*)d_out;

  if (ws_size < WS_NEED) {
    k_dbg<<<4, 256, 0, stream>>>(out, 1.0e6f + (float)(ws_size / 1048576ull));
    return;
  }

  char* ws = (char*)d_ws;
  u32*      wpack = (u32*)(ws + WS_WPACK);
  _Float16* xh    = (_Float16*)(ws + WS_XH);
  _Float16* wihh  = (_Float16*)(ws + WS_WIHH);
  _Float16* igb   = (_Float16*)(ws + WS_IG);
  u32*      pairb = (u32*)(ws + WS_PAIR);

  k_zero<<<16, 256, 0, stream>>>(pairb);
  k_conv_f16<<<8388608 / 256, 256, 0, stream>>>(x, xh, 8388608);
  k_conv_f16<<<3145728 / 256, 256, 0, stream>>>(wih, wihh, 3145728);
  k_pack<<<24576, 256, 0, stream>>>(whh, wpack);
  k_gemm<<<dim3(128, 48), 256, 0, stream>>>(xh, wihh, bias, igb);

  const uint4* wpc = (const uint4*)wpack;
  const _Float16* igc = igb;
  void* kargs[] = {(void*)&wpc, (void*)&igc, (void*)&bias_n, (void*)&pairb};
  hipLaunchCooperativeKernel(k_scan, dim3(256), dim3(512), kargs, 0, stream);

  k_out<<<250, 256, 0, stream>>>(wout, bout, bextra, pairb, out);
}

// Round 3
// 64553.546 us; speedup vs baseline: 1.4109x; 1.4109x over previous
//
#include <hip/hip_runtime.h>
#include <hip/hip_bf16.h>

typedef unsigned int u32;
typedef unsigned short u16;
using half2_t = __attribute__((ext_vector_type(2))) _Float16;
using half8   = __attribute__((ext_vector_type(8))) _Float16;
using f32x4   = __attribute__((ext_vector_type(4))) float;
using u32x4   = __attribute__((ext_vector_type(4))) u32;

// Problem dims
#define TT 16384
#define HDIM 2048
#define N3H 6144
#define ODIM 1000

// Workspace layout (bytes). Total = 318,785,536 (~304 MB)
#define WS_WPACK 0ull                 // 25,165,824  : W_hh packed f16 pairs
#define WS_XH    25165824ull          // 67,108,864  : x as f16
#define WS_WIHH  92274688ull          // 25,165,824  : W_ih as f16
#define WS_IG    117440512ull         // 201,326,592 : igates f16 [T][6144]
#define WS_PAIR  318767104ull         // 16,384      : h publish {tag16|f16} [2][2048] u32
#define WS_NEED  318785536ull

#if __has_builtin(__builtin_amdgcn_fdot2)
__device__ __forceinline__ float fdot2u(u32 a, u32 b, float c) {
  return __builtin_amdgcn_fdot2(__builtin_bit_cast(half2_t, a),
                                __builtin_bit_cast(half2_t, b), c, false);
}
#else
__device__ __forceinline__ float fdot2u(u32 a, u32 b, float c) {
  half2_t x = __builtin_bit_cast(half2_t, a), y = __builtin_bit_cast(half2_t, b);
  return c + (float)x[0] * (float)y[0] + (float)x[1] * (float)y[1];
}
#endif

// Coherent coalesced 16B load: sc0+sc1 bypass (non-coherent) L1/L2, served at
// the device coherence point. Each dword inside is individually atomic, which
// is all the tag-validation scheme needs. vmcnt(0) inside the asm so the
// result regs are valid on return.
__device__ __forceinline__ u32x4 poll_load16(const u32* p) {
  u32x4 r;
  asm volatile("global_load_dwordx4 %0, %1, off sc0 sc1\n\ts_waitcnt vmcnt(0)"
               : "=&v"(r) : "v"(p));
  return r;
}

// ---------------- zero the publish buffers (every launch: clears stale tags) -
__global__ void k_zero(u32* p) {
  p[blockIdx.x * 256 + threadIdx.x] = 0u;  // 4096 dwords
}

// ---------------- fp32 -> f16 convert, 4 elems/thread ------------------------
__global__ __launch_bounds__(256) void k_conv_f16(const float* __restrict__ in,
                                                  _Float16* __restrict__ out,
                                                  int n4) {
  int i = blockIdx.x * 256 + threadIdx.x;
  if (i >= n4) return;
  float4 v = ((const float4*)in)[i];
  u32 lo = (u32)__builtin_bit_cast(u16, (_Float16)v.x) |
           ((u32)__builtin_bit_cast(u16, (_Float16)v.y) << 16);
  u32 hi = (u32)__builtin_bit_cast(u16, (_Float16)v.z) |
           ((u32)__builtin_bit_cast(u16, (_Float16)v.w) << 16);
  ((uint2*)out)[i] = make_uint2(lo, hi);
}

// ---------------- pack W_hh into per-(hrow,wave,lane) f16-pair layout --------
__global__ __launch_bounds__(256) void k_pack(const float* __restrict__ whh,
                                              u32* __restrict__ outp) {
  u32 idx = blockIdx.x * 256 + threadIdx.x;  // < 6,291,456
  u32 hrow = idx / 3072;
  u32 rem = idx - hrow * 3072;
  u32 c = rem >> 8;
  u32 lane = (rem >> 2) & 63;
  u32 q = rem & 3;
  u32 dl = c * 4 + q;
  u32 g = dl >> 4;
  u32 m = dl & 15;
  u32 kp = lane * 16 + m;
  const float* src = whh + (size_t)(g * 2048 + hrow) * 2048 + 2 * kp;
  half2_t p;
  p[0] = (_Float16)src[0];
  p[1] = (_Float16)src[1];
  outp[idx] = __builtin_bit_cast(u32, p);
}

// ---------------- igates GEMM: C[m][n] = sum_k x[m][k]*Wih[n][k] + bias[n] ----
__global__ __launch_bounds__(256) void k_gemm(const _Float16* __restrict__ A,
                                              const _Float16* __restrict__ B,
                                              const float* __restrict__ bias,
                                              _Float16* __restrict__ Cout) {
  __shared__ __align__(16) _Float16 As[128 * 32];
  __shared__ __align__(16) _Float16 Bs[128 * 32];
  const int tid = threadIdx.x;
  const int l = tid & 63, w = tid >> 6;
  const int wr = w >> 1, wc = w & 1;
  const int m0 = blockIdx.x * 128, n0 = blockIdx.y * 128;
  const int srow = tid >> 2;
  const int scol = (tid & 3) << 3;
  f32x4 acc[4][4] = {};

  for (int k0 = 0; k0 < HDIM; k0 += 32) {
    __syncthreads();
    uint4 a0 = *(const uint4*)(A + (size_t)(m0 + srow) * HDIM + k0 + scol);
    uint4 a1 = *(const uint4*)(A + (size_t)(m0 + 64 + srow) * HDIM + k0 + scol);
    uint4 b0 = *(const uint4*)(B + (size_t)(n0 + srow) * HDIM + k0 + scol);
    uint4 b1 = *(const uint4*)(B + (size_t)(n0 + 64 + srow) * HDIM + k0 + scol);
    *(uint4*)(As + srow * 32 + scol) = a0;
    *(uint4*)(As + (64 + srow) * 32 + scol) = a1;
    *(uint4*)(Bs + srow * 32 + scol) = b0;
    *(uint4*)(Bs + (64 + srow) * 32 + scol) = b1;
    __syncthreads();
    half8 av[4], bv[4];
#pragma unroll
    for (int mi = 0; mi < 4; ++mi)
      av[mi] = *(const half8*)(As + (wr * 64 + mi * 16 + (l & 15)) * 32 + (l >> 4) * 8);
#pragma unroll
    for (int ni = 0; ni < 4; ++ni)
      bv[ni] = *(const half8*)(Bs + (wc * 64 + ni * 16 + (l & 15)) * 32 + (l >> 4) * 8);
#pragma unroll
    for (int mi = 0; mi < 4; ++mi)
#pragma unroll
      for (int ni = 0; ni < 4; ++ni)
        acc[mi][ni] = __builtin_amdgcn_mfma_f32_16x16x32_f16(av[mi], bv[ni], acc[mi][ni], 0, 0, 0);
  }
#pragma unroll
  for (int ni = 0; ni < 4; ++ni) {
    int col = n0 + wc * 64 + ni * 16 + (l & 15);
    float bb = bias[col];
#pragma unroll
    for (int mi = 0; mi < 4; ++mi) {
      int rbase = m0 + wr * 64 + mi * 16 + (l >> 4) * 4;
#pragma unroll
      for (int r = 0; r < 4; ++r)
        Cout[(size_t)(rbase + r) * N3H + col] = (_Float16)(acc[mi][ni][r] + bb);
    }
  }
}

// ---------------- persistent GRU scan: 256 WGs x 512 thr, coop launch --------
// Wave w of WG wg owns h-row hrow = wg*8+w. W_hh slice in registers.
// Sync: h published as one atomic dword {tag:u16 = t+1 | value:f16}.
// Consumers poll via coalesced sc0sc1 dwordx4 loads with s_sleep backoff.
__global__ __launch_bounds__(512) void k_scan(const uint4* __restrict__ wpack,
                                              const _Float16* __restrict__ ig,
                                              const float* __restrict__ bias_n,
                                              u32* pair) {
  __shared__ __align__(16) u32 lds_h[1280];  // 1024 f16-pair dwords + pad 4/16
  const int tid = threadIdx.x;
  const int l = tid & 63, w = tid >> 6;
  const int wg = blockIdx.x;
  const int hrow = wg * 8 + w;

  u32 wdw[48];
  {
    const uint4* wp = wpack + (size_t)hrow * 12 * 64 + l;
#pragma unroll
    for (int c = 0; c < 12; ++c) {
      uint4 v = wp[(size_t)c * 64];
      wdw[c * 4] = v.x; wdw[c * 4 + 1] = v.y; wdw[c * 4 + 2] = v.z; wdw[c * 4 + 3] = v.w;
    }
  }
  const float bn = bias_n[hrow];
  float hm = 0.f;  // fp32 master state (valid in lane 0)
  u32 hreg[16];
#pragma unroll
  for (int m = 0; m < 16; ++m) hreg[m] = 0;  // h(0) = 0

  float ig0 = (float)ig[hrow], ig1 = (float)ig[2048 + hrow], ig2 = (float)ig[4096 + hrow];

  for (int t = 0; t < TT; ++t) {
    float igr = ig0, igz = ig1, ign = ig2;
    float a0 = 0.f, a1 = 0.f, a2 = 0.f, b0 = 0.f, b1 = 0.f, b2 = 0.f;
#pragma unroll
    for (int m = 0; m < 16; m += 2) {
      a0 = fdot2u(wdw[m],          hreg[m],     a0);
      b0 = fdot2u(wdw[m + 1],      hreg[m + 1], b0);
      a1 = fdot2u(wdw[16 + m],     hreg[m],     a1);
      b1 = fdot2u(wdw[16 + m + 1], hreg[m + 1], b1);
      a2 = fdot2u(wdw[32 + m],     hreg[m],     a2);
      b2 = fdot2u(wdw[32 + m + 1], hreg[m + 1], b2);
    }
    float s0 = a0 + b0, s1 = a1 + b1, s2 = a2 + b2;
#pragma unroll
    for (int off = 1; off < 64; off <<= 1) {
      s0 += __shfl_xor(s0, off, 64);
      s1 += __shfl_xor(s1, off, 64);
      s2 += __shfl_xor(s2, off, 64);
    }
    u32* pdst = pair + (((t + 1) & 1) << 11);
    if (l == 0) {
      float r = 1.f / (1.f + __expf(-(igr + s0)));
      float z = 1.f / (1.f + __expf(-(igz + s1)));
      float nx = ign + r * (s2 + bn);
      float e = __expf(-2.f * nx);
      float n = (1.f - e) / (1.f + e);
      hm = n + z * (hm - n);
      u32 pk = ((u32)(t + 1) << 16) | (u32)__builtin_bit_cast(u16, (_Float16)hm);
      __hip_atomic_store(pdst + hrow, pk, __ATOMIC_RELAXED, __HIP_MEMORY_SCOPE_AGENT);
    }
    if (t == TT - 1) break;
    {  // prefetch next igates row (normal cached loads, latency hidden by poll)
      const _Float16* igp = ig + (size_t)(t + 1) * N3H;
      ig0 = (float)igp[hrow]; ig1 = (float)igp[2048 + hrow]; ig2 = (float)igp[4096 + hrow];
    }
    // poll own 4 rows; coalesced 16B coherent load, backoff between retries.
    const u32 tgt = (u32)(t + 1) << 16;
    const u32* pp = pdst + 4 * tid;
    __builtin_amdgcn_s_sleep(2);  // publish can't be visible before ~1 RTT
    u32x4 d;
    for (;;) {
      d = poll_load16(pp);
      u32 bad = ((d[0] ^ tgt) | (d[1] ^ tgt) | (d[2] ^ tgt) | (d[3] ^ tgt)) & 0xFFFF0000u;
      if (!bad) break;
      __builtin_amdgcn_s_sleep(2);
    }
    __syncthreads();  // all local waves done reading lds_h of prev step
    u32 p0 = (d[0] & 0xFFFFu) | (d[1] << 16);
    u32 p1 = (d[2] & 0xFFFFu) | (d[3] << 16);
    u32* dst = lds_h + 2 * tid + ((tid >> 3) << 2);  // pad 4 dwords per 16
    dst[0] = p0;
    dst[1] = p1;
    __syncthreads();
#pragma unroll
    for (int i = 0; i < 4; ++i) {
      uint4 v = *(const uint4*)(lds_h + l * 20 + i * 4);
      hreg[i * 4] = v.x; hreg[i * 4 + 1] = v.y; hreg[i * 4 + 2] = v.z; hreg[i * 4 + 3] = v.w;
    }
  }
}

// ---------------- final projection: out = w_out @ h_final + b_out + b_extra --
// h_final is in pair buffer 0 (TT even), f16 in low 16 bits of each dword.
__global__ __launch_bounds__(256) void k_out(const float* __restrict__ wout,
                                             const float* __restrict__ bout,
                                             const float* __restrict__ bextra,
                                             const u32* __restrict__ hp,
                                             float* __restrict__ out) {
  const int l = threadIdx.x & 63;
  const int o = blockIdx.x * 4 + (threadIdx.x >> 6);
  if (o >= ODIM) return;
  const float* wr = wout + (size_t)o * HDIM;
  float acc = 0.f;
#pragma unroll
  for (int i = 0; i < 8; ++i) {
    int k4 = i * 256 + l * 4;
    uint4 hd = *(const uint4*)(hp + k4);
    float4 wv = *(const float4*)(wr + k4);
    acc += wv.x * (float)__builtin_bit_cast(_Float16, (u16)(hd.x & 0xFFFFu));
    acc += wv.y * (float)__builtin_bit_cast(_Float16, (u16)(hd.y & 0xFFFFu));
    acc += wv.z * (float)__builtin_bit_cast(_Float16, (u16)(hd.z & 0xFFFFu));
    acc += wv.w * (float)__builtin_bit_cast(_Float16, (u16)(hd.w & 0xFFFFu));
  }
#pragma unroll
  for (int off = 1; off < 64; off <<= 1) acc += __shfl_xor(acc, off, 64);
  if (l == 0) out[o] = acc + bout[o] + bextra[o];
}

// sentinel if workspace too small: absmax ~= 1e6 + ws_size_in_MB (debug channel)
__global__ void k_dbg(float* out, float v) {
  int i = blockIdx.x * 256 + threadIdx.x;
  if (i < ODIM) out[i] = v;
}

extern "C" void kernel_launch(void* const* d_in, const int* in_sizes, int n_in,
                              void* d_out, int out_size, void* d_ws, size_t ws_size,
                              hipStream_t stream) {
  const float* x      = (const float*)d_in[0];
  const float* wih    = (const float*)d_in[1];
  const float* whh    = (const float*)d_in[2];
  const float* bias   = (const float*)d_in[3];
  const float* bias_n = (const float*)d_in[4];
  const float* wout   = (const float*)d_in[5];
  const float* bout   = (const float*)d_in[6];
  const float* bextra = (const float*)d_in[7];
  float* out = (float*)d_out;

  if (ws_size < WS_NEED) {
    k_dbg<<<4, 256, 0, stream>>>(out, 1.0e6f + (float)(ws_size / 1048576ull));
    return;
  }

  char* ws = (char*)d_ws;
  u32*      wpack = (u32*)(ws + WS_WPACK);
  _Float16* xh    = (_Float16*)(ws + WS_XH);
  _Float16* wihh  = (_Float16*)(ws + WS_WIHH);
  _Float16* igb   = (_Float16*)(ws + WS_IG);
  u32*      pairb = (u32*)(ws + WS_PAIR);

  k_zero<<<16, 256, 0, stream>>>(pairb);
  k_conv_f16<<<8388608 / 256, 256, 0, stream>>>(x, xh, 8388608);
  k_conv_f16<<<3145728 / 256, 256, 0, stream>>>(wih, wihh, 3145728);
  k_pack<<<24576, 256, 0, stream>>>(whh, wpack);
  k_gemm<<<dim3(128, 48), 256, 0, stream>>>(xh, wihh, bias, igb);

  const uint4* wpc = (const uint4*)wpack;
  const _Float16* igc = igb;
  void* kargs[] = {(void*)&wpc, (void*)&igc, (void*)&bias_n, (void*)&pairb};
  hipLaunchCooperativeKernel(k_scan, dim3(256), dim3(512), kargs, 0, stream);

  k_out<<<250, 256, 0, stream>>>(wout, bout, bextra, pairb, out);
}